// Round 10
// baseline (639.965 us; speedup 1.0000x reference)
//
#include <hip/hip_runtime.h>
#include <hip/hip_bf16.h>

#define EPS 1e-5f

typedef _Float16 half_t;
typedef __attribute__((ext_vector_type(8))) _Float16 h16x8;
typedef __attribute__((ext_vector_type(4))) _Float16 h16x4;
typedef __attribute__((ext_vector_type(4))) float f32x4;

__device__ __forceinline__ float relu_f(float x) { return x > 0.f ? x : 0.f; }

// ---------------- workspace layout (float units) ----------------
#define OFF_Y1   0
#define OFF_Y2   17743872
#define OFF_Y3   22179840
#define OFF_Y4   23408640
#define OFF_ST   23715840
#define OFF_WHL  23718912
// aliases inside y1 region (y1 dead after conv2):
#define OFF_A    0
#define OFF_BV   3276800
#define OFF_XG   6553600

// ---------------- prep: zero stats + cast g_w2..4 to f16, swizzled to A-frag lane order ----
// o = (mtile*8+ks)*512 + quad*128 + l15*8 + j  -> wave reads 1KB contiguous per (mtile,ks).
__global__ __launch_bounds__(256) void k_prep(const float* w2, const float* w3,
                                              const float* w4, half_t* whl, float* stats) {
    int idx = blockIdx.x * 256 + threadIdx.x;     // grid exact: 768*256 = 3*65536
    if (idx < 3072) stats[idx] = 0.f;
    int l = idx >> 16, e = idx & 65535;
    const float* w = (l == 0) ? w2 : (l == 1) ? w3 : w4;
    float v = w[e];
    int c = e >> 8, k = e & 255;
    int o = ((c >> 4) * 8 + (k >> 5)) * 512 + ((k >> 3) & 3) * 128 + (c & 15) * 8 + (k & 7);
    whl[l * 65536 + o] = (half_t)v;
}

// ---------------- conv1: 3->24 ch, 75->38, stride2 pad1, 2 images/thread, y1 out f16 ------
__global__ __launch_bounds__(256, 2) void k_conv1(const float* img, const float* w,
                                                  const float* bias, half_t* y1, float* ostats) {
    __shared__ float wl[648], bl[24], red[4][48];
    int tid = threadIdx.x;
    if (tid < 24) bl[tid] = bias[tid];
    for (int i = tid; i < 648; i += 256) wl[i] = w[i];
    __syncthreads();
    int idx = blockIdx.x * 256 + tid;      // 1444*256 = 256*1444 exact (image-pairs)
    int b2 = idx / 1444, rem = idx % 1444;
    int b0 = b2 * 2;
    int oh = rem / 38, ow = rem % 38;
    float acc0[24], acc1[24];
#pragma unroll
    for (int o = 0; o < 24; ++o) { acc0[o] = bl[o]; acc1[o] = bl[o]; }
    for (int ic = 0; ic < 3; ++ic) {
        float p0[9], p1[9];
#pragma unroll
        for (int kh = 0; kh < 3; ++kh) {
            int ih = oh * 2 - 1 + kh;
#pragma unroll
            for (int kw = 0; kw < 3; ++kw) {
                int iw = ow * 2 - 1 + kw;
                bool ok = (unsigned)ih < 75u && (unsigned)iw < 75u;
                p0[kh * 3 + kw] = ok ? img[((b0 * 3 + ic) * 75 + ih) * 75 + iw] : 0.f;
                p1[kh * 3 + kw] = ok ? img[(((b0 + 1) * 3 + ic) * 75 + ih) * 75 + iw] : 0.f;
            }
        }
#pragma unroll
        for (int o = 0; o < 24; ++o)
#pragma unroll
            for (int t = 0; t < 9; ++t) {
                float wv = wl[(o * 3 + ic) * 9 + t];
                acc0[o] += wv * p0[t];
                acc1[o] += wv * p1[t];
            }
    }
    int wave = tid >> 6;
#pragma unroll
    for (int o = 0; o < 24; ++o) {
        acc0[o] = relu_f(acc0[o]);
        acc1[o] = relu_f(acc1[o]);
        y1[(b0 * 24 + o) * 1444 + rem] = (half_t)acc0[o];
        y1[((b0 + 1) * 24 + o) * 1444 + rem] = (half_t)acc1[o];
        float v = acc0[o] + acc1[o];
        float v2 = acc0[o] * acc0[o] + acc1[o] * acc1[o];
#pragma unroll
        for (int off = 1; off < 64; off <<= 1) { v += __shfl_xor(v, off); v2 += __shfl_xor(v2, off); }
        if ((tid & 63) == 0) { red[wave][o] = v; red[wave][24 + o] = v2; }
    }
    __syncthreads();
    if (tid < 48)
        atomicAdd(&ostats[(blockIdx.x & 15) * 48 + tid],
                  red[0][tid] + red[1][tid] + red[2][tid] + red[3][tid]);
}

// ---------------- conv2: 24->24, 38->19, 2 images/thread; f16 in; in-BN folded ------------
__global__ __launch_bounds__(256, 2) void k_conv2(const half_t* yin, const float* w,
                                                  const float* bias, const float* instats,
                                                  const float* bng, const float* bnb,
                                                  float* yout, float* ostats) {
    __shared__ float wl[5184], bl[24], sc[24], sh[24], red[4][48];
    int tid = threadIdx.x;
    if (tid < 24) {
        float s = 0.f, s2 = 0.f;
#pragma unroll
        for (int k = 0; k < 16; ++k) { s += instats[k * 48 + tid]; s2 += instats[k * 48 + 24 + tid]; }
        float mu = s * (1.f / 739328.f);
        float var = s2 * (1.f / 739328.f) - mu * mu;
        float sca = bng[tid] * rsqrtf(var + EPS);
        sc[tid] = sca; sh[tid] = bnb[tid] - mu * sca;
        bl[tid] = bias[tid];
    }
    for (int i = tid; i < 5184; i += 256) wl[i] = w[i];
    __syncthreads();
    int idx = blockIdx.x * 256 + tid;      // 361*256 = 256*361 exact (image-pairs)
    int b2 = idx / 361, rem = idx % 361;
    int b0 = b2 * 2;
    int oh = rem / 19, ow = rem % 19;
    float acc0[24], acc1[24];
#pragma unroll
    for (int o = 0; o < 24; ++o) { acc0[o] = bl[o]; acc1[o] = bl[o]; }
    for (int ic = 0; ic < 24; ++ic) {
        float p0[9], p1[9];
        float scc = sc[ic], shc = sh[ic];
#pragma unroll
        for (int kh = 0; kh < 3; ++kh) {
            int ih = oh * 2 - 1 + kh;
#pragma unroll
            for (int kw = 0; kw < 3; ++kw) {
                int iw = ow * 2 - 1 + kw;
                bool ok = (unsigned)ih < 38u && (unsigned)iw < 38u;
                p0[kh * 3 + kw] = ok ? (float)yin[((b0 * 24 + ic) * 38 + ih) * 38 + iw] * scc + shc : 0.f;
                p1[kh * 3 + kw] = ok ? (float)yin[(((b0 + 1) * 24 + ic) * 38 + ih) * 38 + iw] * scc + shc : 0.f;
            }
        }
#pragma unroll
        for (int o = 0; o < 24; ++o)
#pragma unroll
            for (int t = 0; t < 9; ++t) {
                float wv = wl[(o * 24 + ic) * 9 + t];
                acc0[o] += wv * p0[t];
                acc1[o] += wv * p1[t];
            }
    }
    int wave = tid >> 6;
#pragma unroll
    for (int o = 0; o < 24; ++o) {
        acc0[o] = relu_f(acc0[o]);
        acc1[o] = relu_f(acc1[o]);
        yout[(b0 * 24 + o) * 361 + rem] = acc0[o];
        yout[((b0 + 1) * 24 + o) * 361 + rem] = acc1[o];
        float v = acc0[o] + acc1[o];
        float v2 = acc0[o] * acc0[o] + acc1[o] * acc1[o];
#pragma unroll
        for (int off = 1; off < 64; off <<= 1) { v += __shfl_xor(v, off); v2 += __shfl_xor(v2, off); }
        if ((tid & 63) == 0) { red[wave][o] = v; red[wave][24 + o] = v2; }
    }
    __syncthreads();
    if (tid < 48)
        atomicAdd(&ostats[(blockIdx.x & 15) * 48 + tid],
                  red[0][tid] + red[1][tid] + red[2][tid] + red[3][tid]);
}

// ---------------- conv3/4: 24->24, stride2 pad1; in-BN folded; fused out-stats ------------
__global__ __launch_bounds__(256) void k_conv(const float* yin, const float* w,
                                              const float* bias, const float* instats,
                                              const float* bng, const float* bnb,
                                              float* yout, float* ostats,
                                              int Hin, int Hout, float invN) {
    __shared__ float wl[5184], bl[24], sc[24], sh[24], red[4][48];
    int tid = threadIdx.x;
    if (tid < 24) {
        float s = 0.f, s2 = 0.f;
#pragma unroll
        for (int k = 0; k < 16; ++k) { s += instats[k * 48 + tid]; s2 += instats[k * 48 + 24 + tid]; }
        float mu = s * invN;
        float var = s2 * invN - mu * mu;
        float sca = bng[tid] * rsqrtf(var + EPS);
        sc[tid] = sca; sh[tid] = bnb[tid] - mu * sca;
        bl[tid] = bias[tid];
    }
    for (int i = tid; i < 5184; i += 256) wl[i] = w[i];
    __syncthreads();
    int idx = blockIdx.x * 256 + tid;      // grids exact
    int HWo = Hout * Hout;
    int b = idx / HWo, rem = idx % HWo;
    int oh = rem / Hout, ow = rem % Hout;
    float acc[24];
#pragma unroll
    for (int o = 0; o < 24; ++o) acc[o] = bl[o];
    for (int ic = 0; ic < 24; ++ic) {
        float patch[9];
        float scc = sc[ic], shc = sh[ic];
#pragma unroll
        for (int kh = 0; kh < 3; ++kh) {
            int ih = oh * 2 - 1 + kh;
#pragma unroll
            for (int kw = 0; kw < 3; ++kw) {
                int iw = ow * 2 - 1 + kw;
                bool ok = (unsigned)ih < (unsigned)Hin && (unsigned)iw < (unsigned)Hin;
                patch[kh * 3 + kw] = ok ? yin[((b * 24 + ic) * Hin + ih) * Hin + iw] * scc + shc : 0.f;
            }
        }
#pragma unroll
        for (int o = 0; o < 24; ++o)
#pragma unroll
            for (int t = 0; t < 9; ++t) acc[o] += wl[(o * 24 + ic) * 9 + t] * patch[t];
    }
    int wave = tid >> 6;
#pragma unroll
    for (int o = 0; o < 24; ++o) {
        acc[o] = relu_f(acc[o]);
        yout[(b * 24 + o) * HWo + rem] = acc[o];
        float v = acc[o], v2 = v * v;
#pragma unroll
        for (int off = 1; off < 64; off <<= 1) { v += __shfl_xor(v, off); v2 += __shfl_xor(v2, off); }
        if ((tid & 63) == 0) { red[wave][o] = v; red[wave][24 + o] = v2; }
    }
    __syncthreads();
    if (tid < 48)
        atomicAdd(&ostats[(blockIdx.x & 15) * 48 + tid],
                  red[0][tid] + red[1][tid] + red[2][tid] + red[3][tid]);
}

// ---------------- objects: bn4 + coords once into LDS, project through split g_w1 ----------
__global__ __launch_bounds__(256) void k_obj(const float* y4, const float* qst,
                                             const float* w1, const float* b1,
                                             const float* instats, const float* bng,
                                             const float* bnb, float* A, float* Bv, float* xg) {
    int b = blockIdx.x, tid = threadIdx.x;
    __shared__ float w1l[16128];
    __shared__ float objs[25][28];
    __shared__ float sc[24], sh[24], q[11];
    xg[b * 256 + tid] = 0.f;
    for (int i = tid; i < 16128; i += 256) w1l[i] = w1[i];
    if (tid < 24) {
        float s = 0.f, s2 = 0.f;
#pragma unroll
        for (int k = 0; k < 16; ++k) { s += instats[k * 48 + tid]; s2 += instats[k * 48 + 24 + tid]; }
        float mu = s * (1.f / 12800.f);
        float var = s2 * (1.f / 12800.f) - mu * mu;
        float sca = bng[tid] * rsqrtf(var + EPS);
        sc[tid] = sca; sh[tid] = bnb[tid] - mu * sca;
    }
    if (tid < 11) q[tid] = qst[b * 11 + tid];
    __syncthreads();
    for (int i = tid; i < 600; i += 256) {
        int c = i / 25, p = i % 25;
        objs[p][c] = y4[b * 600 + i] * sc[c] + sh[c];
    }
    if (tid < 25) { objs[tid][24] = ((tid / 5) - 2) * 0.5f; objs[tid][25] = ((tid % 5) - 2) * 0.5f; }
    __syncthreads();
    float wr[63];
#pragma unroll
    for (int k = 0; k < 63; ++k) wr[k] = w1l[tid * 63 + k];
    float qdot = b1[tid];
#pragma unroll
    for (int j = 0; j < 11; ++j) qdot += wr[52 + j] * q[j];
#pragma unroll 1
    for (int p = 0; p < 25; ++p) {
        float a = 0.f, bv = qdot;
#pragma unroll
        for (int k = 0; k < 26; ++k) { a += wr[k] * objs[p][k]; bv += wr[26 + k] * objs[p][k]; }
        A[(b * 25 + p) * 256 + tid] = a;
        Bv[(b * 25 + p) * 256 + tid] = bv;
    }
}

// ---------------- fused g-MLP (R4/R7 structure, 155 us): 512 thr, mi=2, nt=4 ---------------
// W as A-operand (global, pre-swizzled), h as B-operand (LDS, padded +8). C/D: col(l15)=h-row,
// row(quad*4+v)=neuron. Single 36.8 KB h buffer. launch_bounds(512,8): request full 4 blk/CU
// (2048 thr = CU max; LDS 4x36.8=147<160 KB; VGPR measured 40 <= 64 cap -> no spill risk).
__global__ __launch_bounds__(512, 8) void k_g(const float* A, const float* Bv, const half_t* whl,
                                              const float* gb2, const float* gb3,
                                              const float* gb4, float* xg) {
    __shared__ alignas(16) half_t h[64 * 264];
    __shared__ float biasL[3][256];
    int tid = threadIdx.x;
    int blk = blockIdx.x;
    int b = blk / 10, t = blk % 10;
    int r0 = t * 64;
    int rmax = 625 - r0; if (rmax > 64) rmax = 64;
    if (tid < 256) { biasL[0][tid] = gb2[tid]; biasL[2][tid] = gb4[tid]; }
    else biasL[1][tid - 256] = gb3[tid - 256];
    const float* Ab = A + b * 6400;
    const float* Bb = Bv + b * 6400;
#pragma unroll
    for (int it = 0; it < 8; ++it) {
        int e = it * 512 + tid;
        int r = e >> 6, c4 = (e & 63) << 2;
        int pr = r0 + r; if (pr > 624) pr = 624;   // clamp; masked at final sum
        int i = pr % 25, j = pr / 25;
        float4 av = *(const float4*)&Ab[i * 256 + c4];
        float4 bv = *(const float4*)&Bb[j * 256 + c4];
        h16x4 hv = {(half_t)relu_f(av.x + bv.x), (half_t)relu_f(av.y + bv.y),
                    (half_t)relu_f(av.z + bv.z), (half_t)relu_f(av.w + bv.w)};
        *(h16x4*)&h[r * 264 + c4] = hv;
    }
    __syncthreads();
    int wv = tid >> 6, lane = tid & 63;
    int quad = lane >> 4, l15 = lane & 15;
#pragma unroll 1
    for (int layer = 0; layer < 3; ++layer) {
        const half_t* W = whl + layer * 65536;
        f32x4 acc[2][4];
#pragma unroll
        for (int mi = 0; mi < 2; ++mi)
#pragma unroll
            for (int nt = 0; nt < 4; ++nt) acc[mi][nt] = (f32x4){0.f, 0.f, 0.f, 0.f};
#pragma unroll 2
        for (int ks = 0; ks < 8; ++ks) {
            int ko = ks * 32 + quad * 8;
            h16x8 bh[4];
#pragma unroll
            for (int nt = 0; nt < 4; ++nt)
                bh[nt] = *(const h16x8*)&h[(nt * 16 + l15) * 264 + ko];
            h16x8 aw[2];
#pragma unroll
            for (int mi = 0; mi < 2; ++mi)
                aw[mi] = *(const h16x8*)&W[((wv * 2 + mi) * 8 + ks) * 512 + lane * 8];
#pragma unroll
            for (int mi = 0; mi < 2; ++mi)
#pragma unroll
                for (int nt = 0; nt < 4; ++nt)
                    acc[mi][nt] = __builtin_amdgcn_mfma_f32_16x16x32_f16(aw[mi], bh[nt], acc[mi][nt], 0, 0, 0);
        }
        __syncthreads();   // all reads of h done; safe to overwrite
        if (layer < 2) {
#pragma unroll
            for (int mi = 0; mi < 2; ++mi) {
                int c0 = wv * 32 + mi * 16 + quad * 4;
#pragma unroll
                for (int nt = 0; nt < 4; ++nt) {
                    int row = nt * 16 + l15;
                    h16x4 hv;
#pragma unroll
                    for (int v = 0; v < 4; ++v)
                        hv[v] = (half_t)relu_f(acc[mi][nt][v] + biasL[layer][c0 + v]);
                    *(h16x4*)&h[row * 264 + c0] = hv;
                }
            }
            __syncthreads();
        } else {
#pragma unroll
            for (int mi = 0; mi < 2; ++mi) {
                int c0 = wv * 32 + mi * 16 + quad * 4;
#pragma unroll
                for (int v = 0; v < 4; ++v) {
                    float s = 0.f;
#pragma unroll
                    for (int nt = 0; nt < 4; ++nt) {
                        int row = nt * 16 + l15;
                        float x = relu_f(acc[mi][nt][v] + biasL[2][c0 + v]);
                        if (row < rmax) s += x;
                    }
                    s += __shfl_xor(s, 1);
                    s += __shfl_xor(s, 2);
                    s += __shfl_xor(s, 4);
                    s += __shfl_xor(s, 8);
                    if (l15 == 0) atomicAdd(&xg[b * 256 + c0 + v], s);
                }
            }
        }
    }
}

// ---------------- f-MLP + log_softmax (2 batches per block) ----------------
__global__ __launch_bounds__(256) void k_f(const float* xg, const float* fw1, const float* fb1,
                                           const float* fw2, const float* fb2,
                                           const float* fw3, const float* fb3, float* out) {
    int b0 = blockIdx.x * 2, tid = threadIdx.x;
    __shared__ float xb[2][256], h1[2][256], l10[2][10], red[2];
    xb[0][tid] = xg[b0 * 256 + tid];
    xb[1][tid] = xg[(b0 + 1) * 256 + tid];
    __syncthreads();
    float s0 = fb1[tid], s1 = s0;
    {
        const float4* wr = (const float4*)&fw1[tid * 256];
        const float4* x0 = (const float4*)xb[0];
        const float4* x1 = (const float4*)xb[1];
#pragma unroll 8
        for (int k = 0; k < 64; ++k) {
            float4 w = wr[k], a = x0[k], c = x1[k];
            s0 += w.x * a.x + w.y * a.y + w.z * a.z + w.w * a.w;
            s1 += w.x * c.x + w.y * c.y + w.z * c.z + w.w * c.w;
        }
    }
    h1[0][tid] = relu_f(s0);
    h1[1][tid] = relu_f(s1);
    __syncthreads();
    s0 = fb2[tid]; s1 = s0;
    {
        const float4* wr = (const float4*)&fw2[tid * 256];
        const float4* x0 = (const float4*)h1[0];
        const float4* x1 = (const float4*)h1[1];
#pragma unroll 8
        for (int k = 0; k < 64; ++k) {
            float4 w = wr[k], a = x0[k], c = x1[k];
            s0 += w.x * a.x + w.y * a.y + w.z * a.z + w.w * a.w;
            s1 += w.x * c.x + w.y * c.y + w.z * c.z + w.w * c.w;
        }
    }
    __syncthreads();
    xb[0][tid] = relu_f(s0);
    xb[1][tid] = relu_f(s1);
    __syncthreads();
    if (tid < 20) {
        int bb = tid / 10, o = tid % 10;
        float v = fb3[o];
        const float4* wr = (const float4*)&fw3[o * 256];
        const float4* hv = (const float4*)xb[bb];
#pragma unroll 8
        for (int k = 0; k < 64; ++k) {
            float4 w = wr[k], x = hv[k];
            v += w.x * x.x + w.y * x.y + w.z * x.z + w.w * x.w;
        }
        l10[bb][o] = v;
    }
    __syncthreads();
    if (tid < 2) {
        float m = l10[tid][0];
        for (int i = 1; i < 10; ++i) m = fmaxf(m, l10[tid][i]);
        float e = 0.f;
        for (int i = 0; i < 10; ++i) e += expf(l10[tid][i] - m);
        red[tid] = m + logf(e);
    }
    __syncthreads();
    if (tid < 20) {
        int bb = tid / 10, o = tid % 10;
        out[(b0 + bb) * 10 + o] = l10[bb][o] - red[bb];
    }
}

extern "C" void kernel_launch(void* const* d_in, const int* in_sizes, int n_in,
                              void* d_out, int out_size, void* d_ws, size_t ws_size,
                              hipStream_t stream) {
    const float* img = (const float*)d_in[0];
    const float* qst = (const float*)d_in[1];
    const float* cw[4] = {(const float*)d_in[2], (const float*)d_in[6],
                          (const float*)d_in[10], (const float*)d_in[14]};
    const float* cb[4] = {(const float*)d_in[3], (const float*)d_in[7],
                          (const float*)d_in[11], (const float*)d_in[15]};
    const float* bg[4] = {(const float*)d_in[4], (const float*)d_in[8],
                          (const float*)d_in[12], (const float*)d_in[16]};
    const float* bb[4] = {(const float*)d_in[5], (const float*)d_in[9],
                          (const float*)d_in[13], (const float*)d_in[17]};
    const float* gw1 = (const float*)d_in[18];
    const float* gb1 = (const float*)d_in[19];
    const float* gw2 = (const float*)d_in[20];
    const float* gb2 = (const float*)d_in[21];
    const float* gw3 = (const float*)d_in[22];
    const float* gb3 = (const float*)d_in[23];
    const float* gw4 = (const float*)d_in[24];
    const float* gb4 = (const float*)d_in[25];
    const float* fw1 = (const float*)d_in[26];
    const float* fb1 = (const float*)d_in[27];
    const float* fw2 = (const float*)d_in[28];
    const float* fb2 = (const float*)d_in[29];
    const float* fw3 = (const float*)d_in[30];
    const float* fb3 = (const float*)d_in[31];

    float* ws = (float*)d_ws;
    half_t* y1 = (half_t*)(ws + OFF_Y1);   // f16 intermediate (halved traffic)
    float* y2 = ws + OFF_Y2;
    float* y3 = ws + OFF_Y3;
    float* y4 = ws + OFF_Y4;
    float* st = ws + OFF_ST;            // 4 layers * 16 slots * 48
    half_t* whl = (half_t*)(ws + OFF_WHL);
    float* A = ws + OFF_A;              // aliases y1 (dead after conv2)
    float* Bv = ws + OFF_BV;
    float* xg = ws + OFF_XG;
    float* out = (float*)d_out;

    k_prep<<<768, 256, 0, stream>>>(gw2, gw3, gw4, whl, st);
    k_conv1<<<1444, 256, 0, stream>>>(img, cw[0], cb[0], y1, st + 0 * 768);
    k_conv2<<<361, 256, 0, stream>>>(y1, cw[1], cb[1], st + 0 * 768, bg[0], bb[0], y2,
                                     st + 1 * 768);
    k_conv<<<200, 256, 0, stream>>>(y2, cw[2], cb[2], st + 1 * 768, bg[1], bb[1], y3,
                                    st + 2 * 768, 19, 10, 1.f / 184832.f);
    k_conv<<<50, 256, 0, stream>>>(y3, cw[3], cb[3], st + 2 * 768, bg[2], bb[2], y4,
                                   st + 3 * 768, 10, 5, 1.f / 51200.f);
    k_obj<<<512, 256, 0, stream>>>(y4, qst, gw1, gb1, st + 3 * 768, bg[3], bb[3], A, Bv, xg);
    k_g<<<5120, 512, 0, stream>>>(A, Bv, whl, gb2, gb3, gb4, xg);
    k_f<<<256, 256, 0, stream>>>(xg, fw1, fb1, fw2, fb2, fw3, fb3, out);
}

// Round 11
// 618.609 us; speedup vs baseline: 1.0345x; 1.0345x over previous
//
#include <hip/hip_runtime.h>
#include <hip/hip_bf16.h>

#define EPS 1e-5f

typedef _Float16 half_t;
typedef __attribute__((ext_vector_type(8))) _Float16 h16x8;
typedef __attribute__((ext_vector_type(4))) _Float16 h16x4;
typedef __attribute__((ext_vector_type(4))) float f32x4;

__device__ __forceinline__ float relu_f(float x) { return x > 0.f ? x : 0.f; }

// ---------------- workspace layout (float units) ----------------
#define OFF_Y1   0
#define OFF_Y2   17743872
#define OFF_Y3   22179840
#define OFF_Y4   23408640
#define OFF_ST   23715840
#define OFF_WHL  23718912
// aliases inside y1 region (y1 dead after conv2):
#define OFF_A    0
#define OFF_BV   3276800
#define OFF_XG   6553600

// ---------------- prep: zero stats + cast g_w2..4 to f16, swizzled to A-frag lane order ----
// o = (mtile*8+ks)*512 + quad*128 + l15*8 + j  -> wave reads 1KB contiguous per (mtile,ks).
__global__ __launch_bounds__(256) void k_prep(const float* w2, const float* w3,
                                              const float* w4, half_t* whl, float* stats) {
    int idx = blockIdx.x * 256 + threadIdx.x;     // grid exact: 768*256 = 3*65536
    if (idx < 3072) stats[idx] = 0.f;
    int l = idx >> 16, e = idx & 65535;
    const float* w = (l == 0) ? w2 : (l == 1) ? w3 : w4;
    float v = w[e];
    int c = e >> 8, k = e & 255;
    int o = ((c >> 4) * 8 + (k >> 5)) * 512 + ((k >> 3) & 3) * 128 + (c & 15) * 8 + (k & 7);
    whl[l * 65536 + o] = (half_t)v;
}

// ---------------- conv1: 3->24 ch, 75->38, stride2 pad1, 2 images/thread, y1 out f16 ------
__global__ __launch_bounds__(256, 2) void k_conv1(const float* img, const float* w,
                                                  const float* bias, half_t* y1, float* ostats) {
    __shared__ float wl[648], bl[24], red[4][48];
    int tid = threadIdx.x;
    if (tid < 24) bl[tid] = bias[tid];
    for (int i = tid; i < 648; i += 256) wl[i] = w[i];
    __syncthreads();
    int idx = blockIdx.x * 256 + tid;      // 1444*256 = 256*1444 exact (image-pairs)
    int b2 = idx / 1444, rem = idx % 1444;
    int b0 = b2 * 2;
    int oh = rem / 38, ow = rem % 38;
    float acc0[24], acc1[24];
#pragma unroll
    for (int o = 0; o < 24; ++o) { acc0[o] = bl[o]; acc1[o] = bl[o]; }
    for (int ic = 0; ic < 3; ++ic) {
        float p0[9], p1[9];
#pragma unroll
        for (int kh = 0; kh < 3; ++kh) {
            int ih = oh * 2 - 1 + kh;
#pragma unroll
            for (int kw = 0; kw < 3; ++kw) {
                int iw = ow * 2 - 1 + kw;
                bool ok = (unsigned)ih < 75u && (unsigned)iw < 75u;
                p0[kh * 3 + kw] = ok ? img[((b0 * 3 + ic) * 75 + ih) * 75 + iw] : 0.f;
                p1[kh * 3 + kw] = ok ? img[(((b0 + 1) * 3 + ic) * 75 + ih) * 75 + iw] : 0.f;
            }
        }
#pragma unroll
        for (int o = 0; o < 24; ++o)
#pragma unroll
            for (int t = 0; t < 9; ++t) {
                float wv = wl[(o * 3 + ic) * 9 + t];
                acc0[o] += wv * p0[t];
                acc1[o] += wv * p1[t];
            }
    }
    int wave = tid >> 6;
#pragma unroll
    for (int o = 0; o < 24; ++o) {
        acc0[o] = relu_f(acc0[o]);
        acc1[o] = relu_f(acc1[o]);
        y1[(b0 * 24 + o) * 1444 + rem] = (half_t)acc0[o];
        y1[((b0 + 1) * 24 + o) * 1444 + rem] = (half_t)acc1[o];
        float v = acc0[o] + acc1[o];
        float v2 = acc0[o] * acc0[o] + acc1[o] * acc1[o];
#pragma unroll
        for (int off = 1; off < 64; off <<= 1) { v += __shfl_xor(v, off); v2 += __shfl_xor(v2, off); }
        if ((tid & 63) == 0) { red[wave][o] = v; red[wave][24 + o] = v2; }
    }
    __syncthreads();
    if (tid < 48)
        atomicAdd(&ostats[(blockIdx.x & 15) * 48 + tid],
                  red[0][tid] + red[1][tid] + red[2][tid] + red[3][tid]);
}

// ---------------- conv2: 24->24, 38->19, 2 images/thread; f16 in; in-BN folded ------------
__global__ __launch_bounds__(256, 2) void k_conv2(const half_t* yin, const float* w,
                                                  const float* bias, const float* instats,
                                                  const float* bng, const float* bnb,
                                                  float* yout, float* ostats) {
    __shared__ float wl[5184], bl[24], sc[24], sh[24], red[4][48];
    int tid = threadIdx.x;
    if (tid < 24) {
        float s = 0.f, s2 = 0.f;
#pragma unroll
        for (int k = 0; k < 16; ++k) { s += instats[k * 48 + tid]; s2 += instats[k * 48 + 24 + tid]; }
        float mu = s * (1.f / 739328.f);
        float var = s2 * (1.f / 739328.f) - mu * mu;
        float sca = bng[tid] * rsqrtf(var + EPS);
        sc[tid] = sca; sh[tid] = bnb[tid] - mu * sca;
        bl[tid] = bias[tid];
    }
    for (int i = tid; i < 5184; i += 256) wl[i] = w[i];
    __syncthreads();
    int idx = blockIdx.x * 256 + tid;      // 361*256 = 256*361 exact (image-pairs)
    int b2 = idx / 361, rem = idx % 361;
    int b0 = b2 * 2;
    int oh = rem / 19, ow = rem % 19;
    float acc0[24], acc1[24];
#pragma unroll
    for (int o = 0; o < 24; ++o) { acc0[o] = bl[o]; acc1[o] = bl[o]; }
    for (int ic = 0; ic < 24; ++ic) {
        float p0[9], p1[9];
        float scc = sc[ic], shc = sh[ic];
#pragma unroll
        for (int kh = 0; kh < 3; ++kh) {
            int ih = oh * 2 - 1 + kh;
#pragma unroll
            for (int kw = 0; kw < 3; ++kw) {
                int iw = ow * 2 - 1 + kw;
                bool ok = (unsigned)ih < 38u && (unsigned)iw < 38u;
                p0[kh * 3 + kw] = ok ? (float)yin[((b0 * 24 + ic) * 38 + ih) * 38 + iw] * scc + shc : 0.f;
                p1[kh * 3 + kw] = ok ? (float)yin[(((b0 + 1) * 24 + ic) * 38 + ih) * 38 + iw] * scc + shc : 0.f;
            }
        }
#pragma unroll
        for (int o = 0; o < 24; ++o)
#pragma unroll
            for (int t = 0; t < 9; ++t) {
                float wv = wl[(o * 24 + ic) * 9 + t];
                acc0[o] += wv * p0[t];
                acc1[o] += wv * p1[t];
            }
    }
    int wave = tid >> 6;
#pragma unroll
    for (int o = 0; o < 24; ++o) {
        acc0[o] = relu_f(acc0[o]);
        acc1[o] = relu_f(acc1[o]);
        yout[(b0 * 24 + o) * 361 + rem] = acc0[o];
        yout[((b0 + 1) * 24 + o) * 361 + rem] = acc1[o];
        float v = acc0[o] + acc1[o];
        float v2 = acc0[o] * acc0[o] + acc1[o] * acc1[o];
#pragma unroll
        for (int off = 1; off < 64; off <<= 1) { v += __shfl_xor(v, off); v2 += __shfl_xor(v2, off); }
        if ((tid & 63) == 0) { red[wave][o] = v; red[wave][24 + o] = v2; }
    }
    __syncthreads();
    if (tid < 48)
        atomicAdd(&ostats[(blockIdx.x & 15) * 48 + tid],
                  red[0][tid] + red[1][tid] + red[2][tid] + red[3][tid]);
}

// ---------------- conv3/4: 24->24, stride2 pad1; in-BN folded; fused out-stats ------------
__global__ __launch_bounds__(256) void k_conv(const float* yin, const float* w,
                                              const float* bias, const float* instats,
                                              const float* bng, const float* bnb,
                                              float* yout, float* ostats,
                                              int Hin, int Hout, float invN) {
    __shared__ float wl[5184], bl[24], sc[24], sh[24], red[4][48];
    int tid = threadIdx.x;
    if (tid < 24) {
        float s = 0.f, s2 = 0.f;
#pragma unroll
        for (int k = 0; k < 16; ++k) { s += instats[k * 48 + tid]; s2 += instats[k * 48 + 24 + tid]; }
        float mu = s * invN;
        float var = s2 * invN - mu * mu;
        float sca = bng[tid] * rsqrtf(var + EPS);
        sc[tid] = sca; sh[tid] = bnb[tid] - mu * sca;
        bl[tid] = bias[tid];
    }
    for (int i = tid; i < 5184; i += 256) wl[i] = w[i];
    __syncthreads();
    int idx = blockIdx.x * 256 + tid;      // grids exact
    int HWo = Hout * Hout;
    int b = idx / HWo, rem = idx % HWo;
    int oh = rem / Hout, ow = rem % Hout;
    float acc[24];
#pragma unroll
    for (int o = 0; o < 24; ++o) acc[o] = bl[o];
    for (int ic = 0; ic < 24; ++ic) {
        float patch[9];
        float scc = sc[ic], shc = sh[ic];
#pragma unroll
        for (int kh = 0; kh < 3; ++kh) {
            int ih = oh * 2 - 1 + kh;
#pragma unroll
            for (int kw = 0; kw < 3; ++kw) {
                int iw = ow * 2 - 1 + kw;
                bool ok = (unsigned)ih < (unsigned)Hin && (unsigned)iw < (unsigned)Hin;
                patch[kh * 3 + kw] = ok ? yin[((b * 24 + ic) * Hin + ih) * Hin + iw] * scc + shc : 0.f;
            }
        }
#pragma unroll
        for (int o = 0; o < 24; ++o)
#pragma unroll
            for (int t = 0; t < 9; ++t) acc[o] += wl[(o * 24 + ic) * 9 + t] * patch[t];
    }
    int wave = tid >> 6;
#pragma unroll
    for (int o = 0; o < 24; ++o) {
        acc[o] = relu_f(acc[o]);
        yout[(b * 24 + o) * HWo + rem] = acc[o];
        float v = acc[o], v2 = v * v;
#pragma unroll
        for (int off = 1; off < 64; off <<= 1) { v += __shfl_xor(v, off); v2 += __shfl_xor(v2, off); }
        if ((tid & 63) == 0) { red[wave][o] = v; red[wave][24 + o] = v2; }
    }
    __syncthreads();
    if (tid < 48)
        atomicAdd(&ostats[(blockIdx.x & 15) * 48 + tid],
                  red[0][tid] + red[1][tid] + red[2][tid] + red[3][tid]);
}

// ---------------- objects: bn4 + coords once into LDS, project through split g_w1 ----------
__global__ __launch_bounds__(256) void k_obj(const float* y4, const float* qst,
                                             const float* w1, const float* b1,
                                             const float* instats, const float* bng,
                                             const float* bnb, float* A, float* Bv, float* xg) {
    int b = blockIdx.x, tid = threadIdx.x;
    __shared__ float w1l[16128];
    __shared__ float objs[25][28];
    __shared__ float sc[24], sh[24], q[11];
    xg[b * 256 + tid] = 0.f;
    for (int i = tid; i < 16128; i += 256) w1l[i] = w1[i];
    if (tid < 24) {
        float s = 0.f, s2 = 0.f;
#pragma unroll
        for (int k = 0; k < 16; ++k) { s += instats[k * 48 + tid]; s2 += instats[k * 48 + 24 + tid]; }
        float mu = s * (1.f / 12800.f);
        float var = s2 * (1.f / 12800.f) - mu * mu;
        float sca = bng[tid] * rsqrtf(var + EPS);
        sc[tid] = sca; sh[tid] = bnb[tid] - mu * sca;
    }
    if (tid < 11) q[tid] = qst[b * 11 + tid];
    __syncthreads();
    for (int i = tid; i < 600; i += 256) {
        int c = i / 25, p = i % 25;
        objs[p][c] = y4[b * 600 + i] * sc[c] + sh[c];
    }
    if (tid < 25) { objs[tid][24] = ((tid / 5) - 2) * 0.5f; objs[tid][25] = ((tid % 5) - 2) * 0.5f; }
    __syncthreads();
    float wr[63];
#pragma unroll
    for (int k = 0; k < 63; ++k) wr[k] = w1l[tid * 63 + k];
    float qdot = b1[tid];
#pragma unroll
    for (int j = 0; j < 11; ++j) qdot += wr[52 + j] * q[j];
#pragma unroll 1
    for (int p = 0; p < 25; ++p) {
        float a = 0.f, bv = qdot;
#pragma unroll
        for (int k = 0; k < 26; ++k) { a += wr[k] * objs[p][k]; bv += wr[26 + k] * objs[p][k]; }
        A[(b * 25 + p) * 256 + tid] = a;
        Bv[(b * 25 + p) * 256 + tid] = bv;
    }
}

// ---------------- fused g-MLP (R4/R7/R9-exact, 155 us optimum): 512 thr, mi=2, nt=4 --------
// W as A-operand (global, pre-swizzled), h as B-operand (LDS, padded +8). C/D: col(l15)=h-row,
// row(quad*4+v)=neuron. Single 36.8 KB h buffer, launch_bounds(512,6) -> VGPR 40, ~60% occ.
// Closed axes (all regressed, counter-diagnosed): 4x4 acc/wave (R5: spill), mi=4/nt=2 (R6:
// W-stream cost), dbuf 70 KB (R8: occupancy), (512,8) (R10: VGPR 32 + spill).
__global__ __launch_bounds__(512, 6) void k_g(const float* A, const float* Bv, const half_t* whl,
                                              const float* gb2, const float* gb3,
                                              const float* gb4, float* xg) {
    __shared__ alignas(16) half_t h[64 * 264];
    __shared__ float biasL[3][256];
    int tid = threadIdx.x;
    int blk = blockIdx.x;
    int b = blk / 10, t = blk % 10;
    int r0 = t * 64;
    int rmax = 625 - r0; if (rmax > 64) rmax = 64;
    if (tid < 256) { biasL[0][tid] = gb2[tid]; biasL[2][tid] = gb4[tid]; }
    else biasL[1][tid - 256] = gb3[tid - 256];
    const float* Ab = A + b * 6400;
    const float* Bb = Bv + b * 6400;
#pragma unroll
    for (int it = 0; it < 8; ++it) {
        int e = it * 512 + tid;
        int r = e >> 6, c4 = (e & 63) << 2;
        int pr = r0 + r; if (pr > 624) pr = 624;   // clamp; masked at final sum
        int i = pr % 25, j = pr / 25;
        float4 av = *(const float4*)&Ab[i * 256 + c4];
        float4 bv = *(const float4*)&Bb[j * 256 + c4];
        h16x4 hv = {(half_t)relu_f(av.x + bv.x), (half_t)relu_f(av.y + bv.y),
                    (half_t)relu_f(av.z + bv.z), (half_t)relu_f(av.w + bv.w)};
        *(h16x4*)&h[r * 264 + c4] = hv;
    }
    __syncthreads();
    int wv = tid >> 6, lane = tid & 63;
    int quad = lane >> 4, l15 = lane & 15;
#pragma unroll 1
    for (int layer = 0; layer < 3; ++layer) {
        const half_t* W = whl + layer * 65536;
        f32x4 acc[2][4];
#pragma unroll
        for (int mi = 0; mi < 2; ++mi)
#pragma unroll
            for (int nt = 0; nt < 4; ++nt) acc[mi][nt] = (f32x4){0.f, 0.f, 0.f, 0.f};
#pragma unroll 2
        for (int ks = 0; ks < 8; ++ks) {
            int ko = ks * 32 + quad * 8;
            h16x8 bh[4];
#pragma unroll
            for (int nt = 0; nt < 4; ++nt)
                bh[nt] = *(const h16x8*)&h[(nt * 16 + l15) * 264 + ko];
            h16x8 aw[2];
#pragma unroll
            for (int mi = 0; mi < 2; ++mi)
                aw[mi] = *(const h16x8*)&W[((wv * 2 + mi) * 8 + ks) * 512 + lane * 8];
#pragma unroll
            for (int mi = 0; mi < 2; ++mi)
#pragma unroll
                for (int nt = 0; nt < 4; ++nt)
                    acc[mi][nt] = __builtin_amdgcn_mfma_f32_16x16x32_f16(aw[mi], bh[nt], acc[mi][nt], 0, 0, 0);
        }
        __syncthreads();   // all reads of h done; safe to overwrite
        if (layer < 2) {
#pragma unroll
            for (int mi = 0; mi < 2; ++mi) {
                int c0 = wv * 32 + mi * 16 + quad * 4;
#pragma unroll
                for (int nt = 0; nt < 4; ++nt) {
                    int row = nt * 16 + l15;
                    h16x4 hv;
#pragma unroll
                    for (int v = 0; v < 4; ++v)
                        hv[v] = (half_t)relu_f(acc[mi][nt][v] + biasL[layer][c0 + v]);
                    *(h16x4*)&h[row * 264 + c0] = hv;
                }
            }
            __syncthreads();
        } else {
#pragma unroll
            for (int mi = 0; mi < 2; ++mi) {
                int c0 = wv * 32 + mi * 16 + quad * 4;
#pragma unroll
                for (int v = 0; v < 4; ++v) {
                    float s = 0.f;
#pragma unroll
                    for (int nt = 0; nt < 4; ++nt) {
                        int row = nt * 16 + l15;
                        float x = relu_f(acc[mi][nt][v] + biasL[2][c0 + v]);
                        if (row < rmax) s += x;
                    }
                    s += __shfl_xor(s, 1);
                    s += __shfl_xor(s, 2);
                    s += __shfl_xor(s, 4);
                    s += __shfl_xor(s, 8);
                    if (l15 == 0) atomicAdd(&xg[b * 256 + c0 + v], s);
                }
            }
        }
    }
}

// ---------------- f-MLP + log_softmax (2 batches per block) ----------------
__global__ __launch_bounds__(256) void k_f(const float* xg, const float* fw1, const float* fb1,
                                           const float* fw2, const float* fb2,
                                           const float* fw3, const float* fb3, float* out) {
    int b0 = blockIdx.x * 2, tid = threadIdx.x;
    __shared__ float xb[2][256], h1[2][256], l10[2][10], red[2];
    xb[0][tid] = xg[b0 * 256 + tid];
    xb[1][tid] = xg[(b0 + 1) * 256 + tid];
    __syncthreads();
    float s0 = fb1[tid], s1 = s0;
    {
        const float4* wr = (const float4*)&fw1[tid * 256];
        const float4* x0 = (const float4*)xb[0];
        const float4* x1 = (const float4*)xb[1];
#pragma unroll 8
        for (int k = 0; k < 64; ++k) {
            float4 w = wr[k], a = x0[k], c = x1[k];
            s0 += w.x * a.x + w.y * a.y + w.z * a.z + w.w * a.w;
            s1 += w.x * c.x + w.y * c.y + w.z * c.z + w.w * c.w;
        }
    }
    h1[0][tid] = relu_f(s0);
    h1[1][tid] = relu_f(s1);
    __syncthreads();
    s0 = fb2[tid]; s1 = s0;
    {
        const float4* wr = (const float4*)&fw2[tid * 256];
        const float4* x0 = (const float4*)h1[0];
        const float4* x1 = (const float4*)h1[1];
#pragma unroll 8
        for (int k = 0; k < 64; ++k) {
            float4 w = wr[k], a = x0[k], c = x1[k];
            s0 += w.x * a.x + w.y * a.y + w.z * a.z + w.w * a.w;
            s1 += w.x * c.x + w.y * c.y + w.z * c.z + w.w * c.w;
        }
    }
    __syncthreads();
    xb[0][tid] = relu_f(s0);
    xb[1][tid] = relu_f(s1);
    __syncthreads();
    if (tid < 20) {
        int bb = tid / 10, o = tid % 10;
        float v = fb3[o];
        const float4* wr = (const float4*)&fw3[o * 256];
        const float4* hv = (const float4*)xb[bb];
#pragma unroll 8
        for (int k = 0; k < 64; ++k) {
            float4 w = wr[k], x = hv[k];
            v += w.x * x.x + w.y * x.y + w.z * x.z + w.w * x.w;
        }
        l10[bb][o] = v;
    }
    __syncthreads();
    if (tid < 2) {
        float m = l10[tid][0];
        for (int i = 1; i < 10; ++i) m = fmaxf(m, l10[tid][i]);
        float e = 0.f;
        for (int i = 0; i < 10; ++i) e += expf(l10[tid][i] - m);
        red[tid] = m + logf(e);
    }
    __syncthreads();
    if (tid < 20) {
        int bb = tid / 10, o = tid % 10;
        out[(b0 + bb) * 10 + o] = l10[bb][o] - red[bb];
    }
}

extern "C" void kernel_launch(void* const* d_in, const int* in_sizes, int n_in,
                              void* d_out, int out_size, void* d_ws, size_t ws_size,
                              hipStream_t stream) {
    const float* img = (const float*)d_in[0];
    const float* qst = (const float*)d_in[1];
    const float* cw[4] = {(const float*)d_in[2], (const float*)d_in[6],
                          (const float*)d_in[10], (const float*)d_in[14]};
    const float* cb[4] = {(const float*)d_in[3], (const float*)d_in[7],
                          (const float*)d_in[11], (const float*)d_in[15]};
    const float* bg[4] = {(const float*)d_in[4], (const float*)d_in[8],
                          (const float*)d_in[12], (const float*)d_in[16]};
    const float* bb[4] = {(const float*)d_in[5], (const float*)d_in[9],
                          (const float*)d_in[13], (const float*)d_in[17]};
    const float* gw1 = (const float*)d_in[18];
    const float* gb1 = (const float*)d_in[19];
    const float* gw2 = (const float*)d_in[20];
    const float* gb2 = (const float*)d_in[21];
    const float* gw3 = (const float*)d_in[22];
    const float* gb3 = (const float*)d_in[23];
    const float* gw4 = (const float*)d_in[24];
    const float* gb4 = (const float*)d_in[25];
    const float* fw1 = (const float*)d_in[26];
    const float* fb1 = (const float*)d_in[27];
    const float* fw2 = (const float*)d_in[28];
    const float* fb2 = (const float*)d_in[29];
    const float* fw3 = (const float*)d_in[30];
    const float* fb3 = (const float*)d_in[31];

    float* ws = (float*)d_ws;
    half_t* y1 = (half_t*)(ws + OFF_Y1);   // f16 intermediate (halved traffic)
    float* y2 = ws + OFF_Y2;
    float* y3 = ws + OFF_Y3;
    float* y4 = ws + OFF_Y4;
    float* st = ws + OFF_ST;            // 4 layers * 16 slots * 48
    half_t* whl = (half_t*)(ws + OFF_WHL);
    float* A = ws + OFF_A;              // aliases y1 (dead after conv2)
    float* Bv = ws + OFF_BV;
    float* xg = ws + OFF_XG;
    float* out = (float*)d_out;

    k_prep<<<768, 256, 0, stream>>>(gw2, gw3, gw4, whl, st);
    k_conv1<<<1444, 256, 0, stream>>>(img, cw[0], cb[0], y1, st + 0 * 768);
    k_conv2<<<361, 256, 0, stream>>>(y1, cw[1], cb[1], st + 0 * 768, bg[0], bb[0], y2,
                                     st + 1 * 768);
    k_conv<<<200, 256, 0, stream>>>(y2, cw[2], cb[2], st + 1 * 768, bg[1], bb[1], y3,
                                    st + 2 * 768, 19, 10, 1.f / 184832.f);
    k_conv<<<50, 256, 0, stream>>>(y3, cw[3], cb[3], st + 2 * 768, bg[2], bb[2], y4,
                                   st + 3 * 768, 10, 5, 1.f / 51200.f);
    k_obj<<<512, 256, 0, stream>>>(y4, qst, gw1, gb1, st + 3 * 768, bg[3], bb[3], A, Bv, xg);
    k_g<<<5120, 512, 0, stream>>>(A, Bv, whl, gb2, gb3, gb4, xg);
    k_f<<<256, 256, 0, stream>>>(xg, fw1, fb1, fw2, fb2, fw3, fb3, out);
}